// Round 11
// baseline (112.175 us; speedup 1.0000x reference)
//
#include <hip/hip_runtime.h>

// Problem constants
#define N_ 32
#define T_ 300
#define V_ 25
#define C_ 64      // C_IN
#define F_ 128
#define K_ 3
#define NBLK (N_ * T_)   // 9600 blocks: block = 1 timestep, 4 waves = 4 f-quarters

typedef _Float16 f16;
typedef f16  f16x4v __attribute__((ext_vector_type(4)));
typedef f16  f16x8v __attribute__((ext_vector_type(8)));
typedef float f32x4v __attribute__((ext_vector_type(4)));

// workspace byte offsets
#define WS_WT  0        // f16 Wt[384][64]            = 49152 B
#define WS_A2F 49152    // f16 a2frag[3][2][2][64][4] =  6144 B (exact gemm2 B-frag order)

// ---------------- prep: transpose/convert W; A -> B-fragment layout ----------------
// a2frag[(((k*2+s)*2+wt)*64+lane)*4+e] = A[k][v][w], v = s*16+(lane>>4)*4+e, w = wt*16+(lane&15)
// (v>=25 rows MUST be zero — they multiply bias-contaminated h lanes)
__global__ void gcn_prep(const float* __restrict__ A, const float* __restrict__ W,
                         f16* __restrict__ Wt, f16* __restrict__ A2F) {
    int tid = blockIdx.x * blockDim.x + threadIdx.x;
    if (tid < K_ * F_ * C_) {
        int d = tid >> 6, c = tid & 63;
        Wt[tid] = (f16)W[c * (K_ * F_) + d];
    }
    int t2 = tid - K_ * F_ * C_;
    if (t2 >= 0 && t2 < K_ * 2 * 2 * 64 * 4) {
        int e = t2 & 3, lane = (t2 >> 2) & 63, wt = (t2 >> 8) & 1, s = (t2 >> 9) & 1, k = t2 >> 10;
        int v = s * 16 + (lane >> 4) * 4 + e;
        int w = wt * 16 + (lane & 15);
        A2F[t2] = (v < V_ && w < V_) ? (f16)A[(k * V_ + v) * V_ + w] : (f16)0.f;
    }
}

// ---------------- fused, zero-LDS, zero-barrier: wave = (timestep, f-quarter) ----------------
// gemm1 (16x16x32): D1[v][f'] = sum_c x[t][v][c] * Wt[kF+f'][c]   (lane: f'=l15, v=lgr*4+r)
// bias+cvt in regs: h4 = (f16)(D1 + b)  == A-frag of 16x16x16 (m=f'=l15, k=v=lgr*4+e)
// gemm2 (16x16x16, v-steps of 16): accy[f'][w] += h4 x A2frag     (lane: w=l15, f'=lgr*4+r)
// Wt fragments ping-pong-prefetched one (k,ft) step ahead.
__global__ __launch_bounds__(256, 5) void gcn_fused(
    const float* __restrict__ x, const f16* __restrict__ Wt,
    const f16* __restrict__ A2F, const float* __restrict__ b,
    float* __restrict__ y)
{
    const int tid  = threadIdx.x;
    const int lane = tid & 63;
    const int fq   = tid >> 6;        // f-quarter: f = fq*32 + ft*16 + l15
    const int l15  = lane & 15;
    const int lgr  = lane >> 4;       // 0..3

    const int gid  = blockIdx.x;      // timestep = n*T + t
    const float* xt = x + (size_t)gid * (V_ * C_);

    // ---- x A-fragments (loaded once): m=v=vt*16+l15, k-slice c=kt*32+lgr*8+j ----
    f16x8v xf[2][2];
    #pragma unroll
    for (int vt = 0; vt < 2; ++vt) {
        const int v = vt * 16 + l15;
        const bool ok = (v < V_);
        #pragma unroll
        for (int kt = 0; kt < 2; ++kt) {
            float4 lo = {0.f, 0.f, 0.f, 0.f}, hi = {0.f, 0.f, 0.f, 0.f};
            if (ok) {
                const float4* p = (const float4*)(xt + v * C_ + kt * 32 + lgr * 8);
                lo = p[0]; hi = p[1];
            }
            f16x8v f;
            f[0] = (f16)lo.x; f[1] = (f16)lo.y; f[2] = (f16)lo.z; f[3] = (f16)lo.w;
            f[4] = (f16)hi.x; f[5] = (f16)hi.y; f[6] = (f16)hi.z; f[7] = (f16)hi.w;
            xf[vt][kt] = f;
        }
    }

    // ---- bias preload (6 regs): bias for (k, ft) at f = fq*32 + ft*16 + l15 ----
    float bias[K_][2];
    #pragma unroll
    for (int k = 0; k < K_; ++k)
        #pragma unroll
        for (int ft = 0; ft < 2; ++ft)
            bias[k][ft] = b[k * F_ + fq * 32 + ft * 16 + l15];

    f32x4v zero4 = {0.f, 0.f, 0.f, 0.f};
    f32x4v accy[2][2];                 // [ft][wt]
    #pragma unroll
    for (int ft = 0; ft < 2; ++ft)
        #pragma unroll
        for (int wt = 0; wt < 2; ++wt)
            accy[ft][wt] = zero4;

    // Wt fragment loader: row d = k*128 + fq*32 + ft*16 + l15, c-slices lgr*8 + kt*32
    auto loadw = [&](int k, int ft, f16x8v w[2]) {
        const f16* p = Wt + (size_t)(k * F_ + fq * 32 + ft * 16 + l15) * C_ + lgr * 8;
        w[0] = *(const f16x8v*)(p);
        w[1] = *(const f16x8v*)(p + 32);
    };

    // one (k,ft) compute step: gemm1 with wf -> bias+cvt -> gemm2 into accy[ft]
    auto step = [&](int ft, const f16x8v wf[2], float bv, const f16x4v a2w[2][2]) {
        f32x4v acc1[2] = {zero4, zero4};   // [vt]: D1 rows v = vt*16+lgr*4+r
        #pragma unroll
        for (int kt = 0; kt < 2; ++kt)
            #pragma unroll
            for (int vt = 0; vt < 2; ++vt)
                acc1[vt] = __builtin_amdgcn_mfma_f32_16x16x32_f16(
                    xf[vt][kt], wf[kt], acc1[vt], 0, 0, 0);
        #pragma unroll
        for (int s = 0; s < 2; ++s) {
            f16x4v h4;
            #pragma unroll
            for (int e = 0; e < 4; ++e) h4[e] = (f16)(acc1[s][e] + bv);
            #pragma unroll
            for (int wt = 0; wt < 2; ++wt)
                accy[ft][wt] = __builtin_amdgcn_mfma_f32_16x16x16f16(
                    h4, a2w[s][wt], accy[ft][wt], 0, 0, 0);
        }
    };

    f16x8v wA[2], wB[2];
    loadw(0, 0, wA);                       // prologue prefetch

    #pragma unroll 1                       // keep k dynamic: bounded register pressure
    for (int k = 0; k < K_; ++k) {
        // gemm2 B-frags for this k (8B/lane, L2/L1-hot)
        f16x4v a2w[2][2];
        #pragma unroll
        for (int s = 0; s < 2; ++s)
            #pragma unroll
            for (int wt = 0; wt < 2; ++wt)
                a2w[s][wt] = *(const f16x4v*)(A2F + (((size_t)(k * 2 + s) * 2 + wt) * 64 + lane) * 4);

        loadw(k, 1, wB);                   // prefetch ft=1 under ft=0 compute
        step(0, wA, bias[k][0], a2w);

        const int kn = (k + 1 < K_) ? k + 1 : k;   // clamped (last prefetch harmless)
        loadw(kn, 0, wA);                  // prefetch next k's ft=0 under ft=1 compute
        step(1, wB, bias[k][1], a2w);
    }

    // ---- store: lane holds accy[ft][wt] = y[w = wt*16+l15][f = fq*32+ft*16+lgr*4+r] ----
    {
        float* yt = y + (size_t)gid * (V_ * F_);
        #pragma unroll
        for (int wt = 0; wt < 2; ++wt) {
            const int w = wt * 16 + l15;
            if (w < V_) {
                #pragma unroll
                for (int ft = 0; ft < 2; ++ft) {
                    float4 o;
                    o.x = accy[ft][wt][0]; o.y = accy[ft][wt][1];
                    o.z = accy[ft][wt][2]; o.w = accy[ft][wt][3];
                    *(float4*)(yt + (size_t)w * F_ + fq * 32 + ft * 16 + lgr * 4) = o;
                }
            }
        }
    }
}

extern "C" void kernel_launch(void* const* d_in, const int* in_sizes, int n_in,
                              void* d_out, int out_size, void* d_ws, size_t ws_size,
                              hipStream_t stream) {
    const float* x = (const float*)d_in[0];
    const float* A = (const float*)d_in[1];
    const float* W = (const float*)d_in[2];
    const float* b = (const float*)d_in[3];
    float* yout = (float*)d_out;

    f16* Wt  = (f16*)((char*)d_ws + WS_WT);
    f16* A2F = (f16*)((char*)d_ws + WS_A2F);

    const int prep_threads = K_ * F_ * C_ + K_ * 2 * 2 * 64 * 4;  // 27648
    gcn_prep<<<(prep_threads + 255) / 256, 256, 0, stream>>>(A, W, Wt, A2F);
    gcn_fused<<<NBLK, 256, 0, stream>>>(x, Wt, A2F, b, yout);
}